// Round 5
// baseline (2646.455 us; speedup 1.0000x reference)
//
#include <hip/hip_runtime.h>
#include <cmath>

#define TPB 256
#define CSH 10               // coarse bucket = 1024 rows
#define CMAX 512             // max coarse buckets supported by LDS hist (M <= 512*1024)
#define CHUNK 16384          // edges per binsort/count block
#define TPB2 1024            // threads for csr_place3 / scanC

// ---------------- CSR build ----------------
// R1/R2 post-mortem: scattered single-edge global appends are write-amplified
// ~6-7x (every 64B line's writes arrive from different blocks over the whole
// kernel -> no L2 line survives). Write-combining needs TEMPORAL clustering.
// R3 post-mortem: hist3's 9.6M device-scope atomics to a shared 1.2MB counts
// array cost ~32B write-through EACH (299MB measured) -- cross-XCD atomics
// are memory-side transactions. Fix: never do per-element global atomics.
//   1) coarse_count: LDS hist per 16K-edge chunk -> one bulk atomic per
//      (block, coarse bucket) (~172K atomics total).
//   2) scanC: 293-entry scan -> coarse offsets Pc (one tiny block).
//   3) binsort: block-local counting sort; bulk reservation from ccur (=Pc);
//      contiguous ~448B runs written within the block's lifetime (~1.1x amp).
//   4) csr_place3: one block per coarse bucket derives per-row structure
//      LOCALLY (LDS hist of row-low-10 + LDS scan), writes the global P slice,
//      then scatters into final CSR order inside a 262KB window.

// phase 0: coarse histogram. LDS-aggregated; ~586 global atomics per counter.
__global__ __launch_bounds__(TPB) void coarse_count_kernel(
    const int* __restrict__ r0, const int* __restrict__ r1,
    const int* __restrict__ r2, int E, int N, int C, int* __restrict__ Cc) {
  __shared__ int hist[CMAX];
  int tot = 3 * E;
  int t0 = blockIdx.x * CHUNK;
  int t1 = t0 + CHUNK;
  if (t1 > tot) t1 = tot;
  for (int c = threadIdx.x; c < C; c += TPB) hist[c] = 0;
  __syncthreads();
  for (int t = t0 + (int)threadIdx.x; t < t1; t += TPB) {
    int m = (t >= 2 * E) ? 2 : (t >= E) ? 1 : 0;
    int i = t - m * E;
    const int* rr = m == 0 ? r0 : m == 1 ? r1 : r2;
    atomicAdd(&hist[(rr[i] + m * N) >> CSH], 1);
  }
  __syncthreads();
  for (int c = threadIdx.x; c < C; c += TPB) {
    int h = hist[c];
    if (h) atomicAdd(&Cc[c], h);
  }
}

// phase 0b: exclusive scan of the C coarse counts (C <= 1024). Pc[0..C]; ccur=Pc.
__global__ __launch_bounds__(TPB2) void scanC_kernel(
    const int* __restrict__ Cc, int* __restrict__ Pc, int* __restrict__ ccur, int C) {
  __shared__ int lds[TPB2];
  int tid = threadIdx.x;
  int v = (tid < C) ? Cc[tid] : 0;
  lds[tid] = v;
  __syncthreads();
  for (int off = 1; off < TPB2; off <<= 1) {
    int t = (tid >= off) ? lds[tid - off] : 0;
    __syncthreads();
    if (tid >= off) lds[tid] += t;
    __syncthreads();
  }
  int incl = lds[tid];
  int excl = incl - v;
  if (tid < C) { Pc[tid] = excl; ccur[tid] = excl; }
  if (tid == C - 1) Pc[C] = incl;
}

// phase 1: block-local counting sort into coarse-bucket staging runs.
// Record: (col<<CSH | row_low_bits, val) -- 8 B. Requires col < 2^(31-CSH)
// (N=100K << 2^21, ok).
__global__ __launch_bounds__(TPB) void binsort_kernel(
    const int* __restrict__ r0, const int* __restrict__ c0, const float* __restrict__ v0,
    const int* __restrict__ r1, const int* __restrict__ c1, const float* __restrict__ v1,
    const int* __restrict__ r2, const int* __restrict__ c2, const float* __restrict__ v2,
    int E, int N, int C, int* __restrict__ ccur, int2* __restrict__ stage) {
  __shared__ int hist[CMAX];
  int t0 = blockIdx.x * CHUNK;
  int t1 = t0 + CHUNK;
  int tot = 3 * E;
  if (t1 > tot) t1 = tot;
  for (int c = threadIdx.x; c < C; c += TPB) hist[c] = 0;
  __syncthreads();
  // pass A: LDS histogram of this chunk by coarse bucket
  for (int t = t0 + (int)threadIdx.x; t < t1; t += TPB) {
    int m = (t >= 2 * E) ? 2 : (t >= E) ? 1 : 0;
    int i = t - m * E;
    const int* rr = m == 0 ? r0 : m == 1 ? r1 : r2;
    int gr = rr[i] + m * N;
    atomicAdd(&hist[gr >> CSH], 1);
  }
  __syncthreads();
  // bulk reservation: one global atomic per non-empty bucket; hist becomes
  // the block's running cursor per bucket.
  for (int c = threadIdx.x; c < C; c += TPB) {
    int h = hist[c];
    hist[c] = h ? atomicAdd(&ccur[c], h) : 0;
  }
  __syncthreads();
  // pass B: re-read chunk (L2-hot) and stream into reserved runs
  for (int t = t0 + (int)threadIdx.x; t < t1; t += TPB) {
    int m = (t >= 2 * E) ? 2 : (t >= E) ? 1 : 0;
    int i = t - m * E;
    const int* rr = m == 0 ? r0 : m == 1 ? r1 : r2;
    const int* cc = m == 0 ? c0 : m == 1 ? c1 : c2;
    const float* vv = m == 0 ? v0 : m == 1 ? v1 : v2;
    int gr = rr[i] + m * N;
    int pos = atomicAdd(&hist[gr >> CSH], 1);  // LDS
    stage[pos] = make_int2((cc[i] << CSH) | (gr & ((1 << CSH) - 1)),
                           __float_as_int(vv[i]));
  }
}

// phase 2: one block per coarse bucket. Derive per-row structure locally:
// LDS hist of row-low-10 bits -> LDS scan -> write global P slice -> scatter
// the bucket's staging region into final CSR positions (262 KB window).
__global__ __launch_bounds__(TPB2) void csr_place3_kernel(
    const int* __restrict__ Pc, const int2* __restrict__ stage,
    int2* __restrict__ pairs, int* __restrict__ P, int M, int C) {
  __shared__ int h[1 << CSH];
  const int tid = threadIdx.x;
  const int row0 = blockIdx.x << CSH;
  const int start = Pc[blockIdx.x], end = Pc[blockIdx.x + 1];
  h[tid] = 0;
  __syncthreads();
  for (int j = start + tid; j < end; j += TPB2)
    atomicAdd(&h[stage[j].x & ((1 << CSH) - 1)], 1);
  __syncthreads();
  int cnt = h[tid];
  for (int off = 1; off < TPB2; off <<= 1) {  // inclusive Hillis-Steele
    int t = (tid >= off) ? h[tid - off] : 0;
    __syncthreads();
    if (tid >= off) h[tid] += t;
    __syncthreads();
  }
  int cur = start + (h[tid] - cnt);  // start + exclusive prefix
  int row = row0 + tid;
  if (row < M) P[row] = cur;
  if (blockIdx.x == C - 1 && tid == 0) P[M] = end;
  h[tid] = cur;  // own-slot rewrite; no cross-thread read until next sync
  __syncthreads();
  for (int j = start + tid; j < end; j += TPB2) {
    int2 s = stage[j];
    int rl = s.x & ((1 << CSH) - 1);
    int pos = atomicAdd(&h[rl], 1);
    pairs[pos] = make_int2(((unsigned)s.x) >> CSH, s.y);
  }
}

// ---------------- dense GEMM: C[nrows,128] = A @ W (+bias) ----------------
// block 256 thr, tile 128 rows x 128 cols, thread 8x8.
// W staged in 32 KB LDS chunks (k-depth 64).
// Column split {cg*4, 64+cg*4}: 16 lanes sweep all 32 banks -> 2-way LDS
// aliasing (free per m136).
// NOTE: do NOT unroll the k4 loop — unrolling hoists 8 iterations of a[8]
// float4 A-loads, VGPR 256 + spill traffic.

__global__ __launch_bounds__(TPB) void gemm128_kernel(
    const float* __restrict__ A, const float* __restrict__ W,
    const float* __restrict__ bias, float* __restrict__ C, int nrows) {
  __shared__ float sW[64 * 128];
  const int cg = threadIdx.x & 15;
  const int rg = threadIdx.x >> 4;
  const int cA = cg * 4, cB = 64 + cg * 4;
  const int row0 = blockIdx.x * 128 + rg * 8;
  float acc[8][8];
#pragma unroll
  for (int j = 0; j < 8; ++j)
#pragma unroll
    for (int i = 0; i < 8; ++i) acc[j][i] = 0.f;

#pragma unroll 1
  for (int kc = 0; kc < 128; kc += 64) {
    for (int i = threadIdx.x * 4; i < 64 * 128; i += TPB * 4)
      *(float4*)&sW[i] = *(const float4*)&W[kc * 128 + i];
    __syncthreads();
#pragma unroll 1
    for (int k4 = 0; k4 < 64; k4 += 4) {
      float4 a[8];
#pragma unroll
      for (int j = 0; j < 8; ++j) {
        int r = row0 + j;
        a[j] = (r < nrows) ? *(const float4*)&A[(size_t)r * 128 + kc + k4]
                           : make_float4(0.f, 0.f, 0.f, 0.f);
      }
#pragma unroll
      for (int kk = 0; kk < 4; ++kk) {
        float4 w0 = *(const float4*)&sW[(k4 + kk) * 128 + cA];
        float4 w1 = *(const float4*)&sW[(k4 + kk) * 128 + cB];
#pragma unroll
        for (int j = 0; j < 8; ++j) {
          float aj = (kk == 0) ? a[j].x : (kk == 1) ? a[j].y : (kk == 2) ? a[j].z : a[j].w;
          acc[j][0] = fmaf(aj, w0.x, acc[j][0]);
          acc[j][1] = fmaf(aj, w0.y, acc[j][1]);
          acc[j][2] = fmaf(aj, w0.z, acc[j][2]);
          acc[j][3] = fmaf(aj, w0.w, acc[j][3]);
          acc[j][4] = fmaf(aj, w1.x, acc[j][4]);
          acc[j][5] = fmaf(aj, w1.y, acc[j][5]);
          acc[j][6] = fmaf(aj, w1.z, acc[j][6]);
          acc[j][7] = fmaf(aj, w1.w, acc[j][7]);
        }
      }
    }
    __syncthreads();
  }
  float bv[8];
  if (bias) {
    *(float4*)&bv[0] = *(const float4*)&bias[cA];
    *(float4*)&bv[4] = *(const float4*)&bias[cB];
  } else {
#pragma unroll
    for (int i = 0; i < 8; ++i) bv[i] = 0.f;
  }
#pragma unroll
  for (int j = 0; j < 8; ++j) {
    int r = row0 + j;
    if (r < nrows) {
      *(float4*)&C[(size_t)r * 128 + cA] =
          make_float4(acc[j][0] + bv[0], acc[j][1] + bv[1], acc[j][2] + bv[2], acc[j][3] + bv[3]);
      *(float4*)&C[(size_t)r * 128 + cB] =
          make_float4(acc[j][4] + bv[4], acc[j][5] + bv[5], acc[j][6] + bv[6], acc[j][7] + bv[7]);
    }
  }
}

// ---------------- fusion: score[v][n] = w2 . tanh(x[v,n,:] @ W1 + b1) ----------------

__global__ __launch_bounds__(TPB) void fusion_score_kernel(
    const float* __restrict__ x, const float* __restrict__ W1,
    const float* __restrict__ b1, const float* __restrict__ w2,
    float* __restrict__ score, int nrows) {
  __shared__ float sW[64 * 128];
  const int v = blockIdx.y;
  const float* A = x + (size_t)v * nrows * 128;
  const int cg = threadIdx.x & 15;
  const int rg = threadIdx.x >> 4;
  const int cA = cg * 4, cB = 64 + cg * 4;
  const int row0 = blockIdx.x * 128 + rg * 8;
  float acc[8][8];
#pragma unroll
  for (int j = 0; j < 8; ++j)
#pragma unroll
    for (int i = 0; i < 8; ++i) acc[j][i] = 0.f;

#pragma unroll 1
  for (int kc = 0; kc < 128; kc += 64) {
    for (int i = threadIdx.x * 4; i < 64 * 128; i += TPB * 4)
      *(float4*)&sW[i] = *(const float4*)&W1[kc * 128 + i];
    __syncthreads();
#pragma unroll 1
    for (int k4 = 0; k4 < 64; k4 += 4) {
      float4 a[8];
#pragma unroll
      for (int j = 0; j < 8; ++j) {
        int r = row0 + j;
        a[j] = (r < nrows) ? *(const float4*)&A[(size_t)r * 128 + kc + k4]
                           : make_float4(0.f, 0.f, 0.f, 0.f);
      }
#pragma unroll
      for (int kk = 0; kk < 4; ++kk) {
        float4 w0 = *(const float4*)&sW[(k4 + kk) * 128 + cA];
        float4 w1 = *(const float4*)&sW[(k4 + kk) * 128 + cB];
#pragma unroll
        for (int j = 0; j < 8; ++j) {
          float aj = (kk == 0) ? a[j].x : (kk == 1) ? a[j].y : (kk == 2) ? a[j].z : a[j].w;
          acc[j][0] = fmaf(aj, w0.x, acc[j][0]);
          acc[j][1] = fmaf(aj, w0.y, acc[j][1]);
          acc[j][2] = fmaf(aj, w0.z, acc[j][2]);
          acc[j][3] = fmaf(aj, w0.w, acc[j][3]);
          acc[j][4] = fmaf(aj, w1.x, acc[j][4]);
          acc[j][5] = fmaf(aj, w1.y, acc[j][5]);
          acc[j][6] = fmaf(aj, w1.z, acc[j][6]);
          acc[j][7] = fmaf(aj, w1.w, acc[j][7]);
        }
      }
    }
    __syncthreads();
  }
  float bb[8], ww[8];
  *(float4*)&bb[0] = *(const float4*)&b1[cA];
  *(float4*)&bb[4] = *(const float4*)&b1[cB];
  *(float4*)&ww[0] = *(const float4*)&w2[cA];
  *(float4*)&ww[4] = *(const float4*)&w2[cB];
#pragma unroll
  for (int j = 0; j < 8; ++j) {
    float p = 0.f;
#pragma unroll
    for (int i = 0; i < 8; ++i) p += tanhf(acc[j][i] + bb[i]) * ww[i];
#pragma unroll
    for (int off = 8; off > 0; off >>= 1) p += __shfl_down(p, off, 16);
    if (cg == 0 && row0 + j < nrows) score[(size_t)v * nrows + row0 + j] = p;
  }
}

// softmax over 2 views + weighted sum (b2 cancels in the 2-way softmax)
__global__ void combine_kernel(const float* __restrict__ x, const float* __restrict__ score,
                               float* __restrict__ fused, int nrows) {
  int i = blockIdx.x * TPB + threadIdx.x;  // over nrows*32 float4s
  if (i >= nrows * 32) return;
  int n = i >> 5;
  float s0 = score[n], s1 = score[nrows + n];
  float m = fmaxf(s0, s1);
  float e0 = expf(s0 - m), e1 = expf(s1 - m);
  float inv = 1.f / (e0 + e1);
  float w0 = e0 * inv, w1 = e1 * inv;
  float4 a = ((const float4*)x)[i];
  float4 b = ((const float4*)x)[(size_t)nrows * 32 + i];
  ((float4*)fused)[i] = make_float4(w0 * a.x + w1 * b.x, w0 * a.y + w1 * b.y,
                                    w0 * a.z + w1 * b.z, w0 * a.w + w1 * b.w);
}

// ---------------- spmm: y[r,:] = (relu?) sum val * x[col,:] (+add0 +add1) ----------------
// one 32-lane half-wave per row; lanes hold float4 (128 cols / 32 lanes).
// R4 post-mortem: VALUBusy 11%, fetch 3.4 TB/s << ceiling with coalesced 512B
// gathers -> latency-bound. The old per-edge load->FMA chain kept only ~1
// outstanding load per wave. Fix: 8-deep gather batches (xv[8], statically
// indexed after unroll) -> 8 in-flight loads/wave. Tail is branch-free:
// lanes hl >= nrem hold pr=(0,0), so shfl-padding yields c=0,v=0 (free
// broadcast load of row 0, FMA contributes 0).

__global__ __launch_bounds__(TPB) void spmm_kernel(
    const int* __restrict__ ptr, const int2* __restrict__ pairs,
    const float* __restrict__ x, float* __restrict__ y, int nrows, int do_relu,
    const float* __restrict__ add0, const float* __restrict__ add1) {
  int row = (blockIdx.x * TPB + threadIdx.x) >> 5;
  int hl = threadIdx.x & 31;
  if (row >= nrows) return;
  int start = ptr[row], end = ptr[row + 1];
  float ax = 0.f, ay = 0.f, az = 0.f, aw = 0.f;
  for (int j = start; j < end; j += 32) {
    int nrem = end - j;
    if (nrem > 32) nrem = 32;
    int2 pr = make_int2(0, 0);
    if (hl < nrem) pr = pairs[j + hl];
    for (int t0 = 0; t0 < nrem; t0 += 8) {
      float4 xv[8];
      float vv[8];
#pragma unroll
      for (int k = 0; k < 8; ++k) {
        int c = __shfl(pr.x, t0 + k, 32);
        vv[k] = __int_as_float(__shfl(pr.y, t0 + k, 32));
        xv[k] = *(const float4*)&x[(size_t)c * 128 + hl * 4];
      }
#pragma unroll
      for (int k = 0; k < 8; ++k) {
        ax = fmaf(vv[k], xv[k].x, ax);
        ay = fmaf(vv[k], xv[k].y, ay);
        az = fmaf(vv[k], xv[k].z, az);
        aw = fmaf(vv[k], xv[k].w, aw);
      }
    }
  }
  if (do_relu) {
    ax = fmaxf(ax, 0.f); ay = fmaxf(ay, 0.f);
    az = fmaxf(az, 0.f); aw = fmaxf(aw, 0.f);
  }
  size_t o = (size_t)row * 128 + hl * 4;
  if (add0) { float4 t = *(const float4*)&add0[o]; ax += t.x; ay += t.y; az += t.z; aw += t.w; }
  if (add1) { float4 t = *(const float4*)&add1[o]; ax += t.x; ay += t.y; az += t.z; aw += t.w; }
  *(float4*)&y[o] = make_float4(ax, ay, az, aw);
}

// ---------------- launch ----------------

extern "C" void kernel_launch(void* const* d_in, const int* in_sizes, int n_in,
                              void* d_out, int out_size, void* d_ws, size_t ws_size,
                              hipStream_t stream) {
  const float* x   = (const float*)d_in[0];
  const float* fw1 = (const float*)d_in[1];
  const float* fb1 = (const float*)d_in[2];
  const float* fw2 = (const float*)d_in[3];
  // d_in[4] = fusion_b2: cancels in 2-way softmax
  const float* hgw = (const float*)d_in[5];
  const float* lgw = (const float*)d_in[6];
  const float* lgb = (const float*)d_in[7];
  const float* c1v = (const float*)d_in[8];
  const float* c2v = (const float*)d_in[9];
  const float* lgv = (const float*)d_in[10];
  const int* c1r = (const int*)d_in[11];
  const int* c1c = (const int*)d_in[12];
  const int* c2r = (const int*)d_in[13];
  const int* c2c = (const int*)d_in[14];
  const int* lgr = (const int*)d_in[15];
  const int* lgc = (const int*)d_in[16];

  const int N = in_sizes[0] / 256;  // x is [2,N,128]
  const int E = in_sizes[8];
  const int M = 3 * N;
  const int C = (M + (1 << CSH) - 1) >> CSH;  // coarse buckets (293 for N=100K)

  char* ws = (char*)d_ws;
  size_t off = 0;
  auto alloc = [&](size_t bytes) -> void* {
    void* p = ws + off;
    off += (bytes + 511) & ~(size_t)511;
    return p;
  };
  int* P      = (int*)alloc((size_t)(M + 1) * 4);
  int* Cc     = (int*)alloc((size_t)(C + 1) * 4);
  int* Pc     = (int*)alloc((size_t)(C + 1) * 4);
  int* ccur   = (int*)alloc((size_t)(C + 1) * 4);
  int2* pairs = (int2*)alloc((size_t)3 * E * 8);
  float* score = (float*)alloc((size_t)2 * N * 4);
  float* Fbase = (float*)alloc((size_t)3 * N * 128 * 4);
  float* F0 = Fbase;
  float* F1 = Fbase + (size_t)N * 128;
  float* F2 = Fbase + (size_t)2 * N * 128;
  // CSR-build staging aliases the F buffers: the build completes (stream-
  // ordered) before fusion/combine first write F0/F1/F2.
  // stage: 3E*8 = 76.8 MB <= F region 153.6 MB.
  int2* stage = (int2*)Fbase;
  float* outH = (float*)d_out;
  float* outA = (float*)d_out + (size_t)N * 128;

  // ---- CSR build for [coef1 | coef2 | lg] concatenated ----
  hipMemsetAsync(Cc, 0, (size_t)(C + 1) * 4, stream);
  int NBS = (3 * E + CHUNK - 1) / CHUNK;
  coarse_count_kernel<<<NBS, TPB, 0, stream>>>(c1r, c2r, lgr, E, N, C, Cc);
  scanC_kernel<<<1, TPB2, 0, stream>>>(Cc, Pc, ccur, C);
  binsort_kernel<<<NBS, TPB, 0, stream>>>(c1r, c1c, c1v, c2r, c2c, c2v,
                                          lgr, lgc, lgv, E, N, C, ccur, stage);
  csr_place3_kernel<<<C, TPB2, 0, stream>>>(Pc, stage, pairs, P, M, C);

  // ---- fusion ----
  dim3 gf((N + 127) / 128, 2);
  fusion_score_kernel<<<gf, TPB, 0, stream>>>(x, fw1, fb1, fw2, score, N);
  combine_kernel<<<(N * 32 + TPB - 1) / TPB, TPB, 0, stream>>>(x, score, F0, N);

  int gg = (N + 127) / 128;
  int gs = (N + 7) / 8;  // spmm: 8 half-waves/block, half-wave per row

  // ---- HGCN ----
  gemm128_kernel<<<gg, TPB, 0, stream>>>(F0, hgw + 0 * 16384, nullptr, F1, N);
  spmm_kernel<<<gs, TPB, 0, stream>>>(P, pairs, F1, F2, N, 1, nullptr, nullptr);      // h1
  gemm128_kernel<<<gg, TPB, 0, stream>>>(F2, hgw + 1 * 16384, nullptr, F1, N);
  spmm_kernel<<<gs, TPB, 0, stream>>>(P, pairs, F1, F2, N, 1, nullptr, nullptr);      // h2
  gemm128_kernel<<<gg, TPB, 0, stream>>>(F2, hgw + 2 * 16384, nullptr, F1, N);
  spmm_kernel<<<gs, TPB, 0, stream>>>(P, pairs, F1, outH, N, 1, nullptr, nullptr);    // h3 -> out[0:N]
  spmm_kernel<<<gs, TPB, 0, stream>>>(P + N, pairs, outH, F0, N, 1, nullptr, nullptr); // y

  // ---- LineConv ----
  gemm128_kernel<<<gg, TPB, 0, stream>>>(F0, lgw + 0 * 16384, lgb + 0, F1, N);
  spmm_kernel<<<gs, TPB, 0, stream>>>(P + 2 * N, pairs, F1, F2, N, 0, nullptr, nullptr); // cur1
  gemm128_kernel<<<gg, TPB, 0, stream>>>(F2, lgw + 1 * 16384, lgb + 128, F1, N);
  // cur2 + y + cur1 -> out[N:2N]
  spmm_kernel<<<gs, TPB, 0, stream>>>(P + 2 * N, pairs, F1, outA, N, 0, F0, F2);
}